// Round 2
// baseline (126.238 us; speedup 1.0000x reference)
//
#include <hip/hip_runtime.h>
#include <hip/hip_bf16.h>

// One thread = one particle. 256 particles/block.
// LDS staging: 256*9 floats in (float4-coalesced), compute in registers,
// write f32 results back into same LDS slots, float4-coalesced stores.
__global__ __launch_bounds__(256) void physics_svd_kernel(
    const float* __restrict__ gF,
    const float* __restrict__ p_Elog,
    const float* __restrict__ p_nu,
    const float* __restrict__ p_ys,
    const float* __restrict__ p_alpha,
    const float* __restrict__ p_coh,
    float* __restrict__ gOut,
    int B)
{
    __shared__ __align__(16) float lds[2304];   // 256 particles * 9 floats

    const int tid   = threadIdx.x;
    const int pbase = blockIdx.x * 256;          // first particle of this block
    const int nhere = min(256, B - pbase);
    const int nflt  = nhere * 9;

    // ---- phase 1: stage F into LDS, coalesced ----
    if (nhere == 256) {
        const float4* g4 = reinterpret_cast<const float4*>(gF + (size_t)pbase * 9);
        float4* l4 = reinterpret_cast<float4*>(lds);
        l4[tid]       = g4[tid];
        l4[tid + 256] = g4[tid + 256];
        if (tid < 64) l4[tid + 512] = g4[tid + 512];
    } else {
        for (int j = tid; j < nflt; j += 256) lds[j] = gF[(size_t)pbase * 9 + j];
    }
    __syncthreads();

    // material scalars (uniform broadcast loads)
    const float E  = __expf(p_Elog[0]);
    const float nu = p_nu[0];
    const float ys = p_ys[0];
    const float al = p_alpha[0];
    const float co = p_coh[0];
    const float mu = E / (2.0f * (1.0f + nu));
    const float la = E * nu / ((1.0f + nu) * (1.0f - 2.0f * nu));

    if (tid < nhere) {
        float f[9];
        #pragma unroll
        for (int k = 0; k < 9; ++k) f[k] = lds[tid * 9 + k];

        // S = F^T F (symmetric, 6 uniques)
        float a00 = f[0]*f[0] + f[3]*f[3] + f[6]*f[6];
        float a01 = f[0]*f[1] + f[3]*f[4] + f[6]*f[7];
        float a02 = f[0]*f[2] + f[3]*f[5] + f[6]*f[8];
        float a11 = f[1]*f[1] + f[4]*f[4] + f[7]*f[7];
        float a12 = f[1]*f[2] + f[4]*f[5] + f[7]*f[8];
        float a22 = f[2]*f[2] + f[5]*f[5] + f[8]*f[8];

        // V accumulates Jacobi rotations (orthogonal)
        float v00=1.f, v01=0.f, v02=0.f;
        float v10=0.f, v11=1.f, v12=0.f;
        float v20=0.f, v21=0.f, v22=1.f;

        #pragma unroll
        for (int sweep = 0; sweep < 4; ++sweep) {
            // (p,q) = (0,1), other k = 2
            {
                float apq = a01;
                if (apq != 0.0f) {
                    float theta = (a11 - a00) / (2.0f * apq);
                    float t = copysignf(1.0f, theta) / (fabsf(theta) + sqrtf(theta*theta + 1.0f));
                    float c = rsqrtf(t*t + 1.0f);
                    float s = t * c;
                    a00 -= t * apq;  a11 += t * apq;  a01 = 0.0f;
                    float pk = a02, qk = a12;
                    a02 = c*pk - s*qk;  a12 = s*pk + c*qk;
                    float tmp;
                    tmp = v00; v00 = c*tmp - s*v01; v01 = s*tmp + c*v01;
                    tmp = v10; v10 = c*tmp - s*v11; v11 = s*tmp + c*v11;
                    tmp = v20; v20 = c*tmp - s*v21; v21 = s*tmp + c*v21;
                }
            }
            // (p,q) = (0,2), other k = 1
            {
                float apq = a02;
                if (apq != 0.0f) {
                    float theta = (a22 - a00) / (2.0f * apq);
                    float t = copysignf(1.0f, theta) / (fabsf(theta) + sqrtf(theta*theta + 1.0f));
                    float c = rsqrtf(t*t + 1.0f);
                    float s = t * c;
                    a00 -= t * apq;  a22 += t * apq;  a02 = 0.0f;
                    float pk = a01, qk = a12;
                    a01 = c*pk - s*qk;  a12 = s*pk + c*qk;
                    float tmp;
                    tmp = v00; v00 = c*tmp - s*v02; v02 = s*tmp + c*v02;
                    tmp = v10; v10 = c*tmp - s*v12; v12 = s*tmp + c*v12;
                    tmp = v20; v20 = c*tmp - s*v22; v22 = s*tmp + c*v22;
                }
            }
            // (p,q) = (1,2), other k = 0
            {
                float apq = a12;
                if (apq != 0.0f) {
                    float theta = (a22 - a11) / (2.0f * apq);
                    float t = copysignf(1.0f, theta) / (fabsf(theta) + sqrtf(theta*theta + 1.0f));
                    float c = rsqrtf(t*t + 1.0f);
                    float s = t * c;
                    a11 -= t * apq;  a22 += t * apq;  a12 = 0.0f;
                    float pk = a01, qk = a02;
                    a01 = c*pk - s*qk;  a02 = s*pk + c*qk;
                    float tmp;
                    tmp = v01; v01 = c*tmp - s*v02; v02 = s*tmp + c*v02;
                    tmp = v11; v11 = c*tmp - s*v12; v12 = s*tmp + c*v12;
                    tmp = v21; v21 = c*tmp - s*v22; v22 = s*tmp + c*v22;
                }
            }
        }

        float sig0 = sqrtf(fmaxf(a00, 0.0f));
        float sig1 = sqrtf(fmaxf(a11, 0.0f));
        float sig2 = sqrtf(fmaxf(a22, 0.0f));

        // ---- plasticine (von Mises) ----
        float sp0 = fmaxf(sig0, 0.01f), sp1 = fmaxf(sig1, 0.01f), sp2 = fmaxf(sig2, 0.01f);
        float e0 = __logf(sp0), e1 = __logf(sp1), e2 = __logf(sp2);
        float tr3 = (e0 + e1 + e2) * (1.0f/3.0f);
        float b0 = e0 - tr3, b1 = e1 - tr3, b2 = e2 - tr3;
        float bn = sqrtf(b0*b0 + b1*b1 + b2*b2) + 1e-5f;
        float dgam = bn - ys / (2.0f * mu);
        float gp0, gp1, gp2;
        if (dgam > 0.0f) {
            float r = dgam / bn;
            gp0 = __expf(e0 - r*b0);
            gp1 = __expf(e1 - r*b1);
            gp2 = __expf(e2 - r*b2);
        } else { gp0 = sp0; gp1 = sp1; gp2 = sp2; }

        // ---- sand (Drucker-Prager) ----
        float ss0 = fmaxf(sig0, 0.05f), ss1 = fmaxf(sig1, 0.05f), ss2 = fmaxf(sig2, 0.05f);
        float h0 = __logf(ss0), h1 = __logf(ss1), h2 = __logf(ss2);
        float trs = h0 + h1 + h2;
        float t3 = trs * (1.0f/3.0f);
        float hb0 = h0 - t3, hb1 = h1 - t3, hb2 = h2 - t3;
        float hn = sqrtf(hb0*hb0 + hb1*hb1 + hb2*hb2);
        float st = trs - 3.0f * co;
        float gs0, gs1, gs2;
        if (st < 0.0f) {
            float dg = hn + (3.0f*la + 2.0f*mu) / (2.0f*mu) * st * al;
            float r = fmaxf(dg, 0.0f) / hn;
            gs0 = __expf(h0 - r*hb0);
            gs1 = __expf(h1 - r*hb1);
            gs2 = __expf(h2 - r*hb2);
        } else {
            float ec = __expf(co);
            gs0 = ec; gs1 = ec; gs2 = ec;
        }

        // combined spectral weights: U diag(g) V^T = F V diag(g/s) V^T
        float w0 = (0.5f*gp0 + 0.3f*gs0) / sig0;
        float w1 = (0.5f*gp1 + 0.3f*gs1) / sig1;
        float w2 = (0.5f*gp2 + 0.3f*gs2) / sig2;

        // water: 0.2 * J^(1/3) * I
        float J = f[0]*(f[4]*f[8] - f[5]*f[7])
                - f[1]*(f[3]*f[8] - f[5]*f[6])
                + f[2]*(f[3]*f[7] - f[4]*f[6]);
        float wd = 0.2f * __powf(J, 1.0f/3.0f);

        // T = (F V) * diag(w)
        float t00 = (f[0]*v00 + f[1]*v10 + f[2]*v20) * w0;
        float t01 = (f[0]*v01 + f[1]*v11 + f[2]*v21) * w1;
        float t02 = (f[0]*v02 + f[1]*v12 + f[2]*v22) * w2;
        float t10 = (f[3]*v00 + f[4]*v10 + f[5]*v20) * w0;
        float t11 = (f[3]*v01 + f[4]*v11 + f[5]*v21) * w1;
        float t12 = (f[3]*v02 + f[4]*v12 + f[5]*v22) * w2;
        float t20 = (f[6]*v00 + f[7]*v10 + f[8]*v20) * w0;
        float t21 = (f[6]*v01 + f[7]*v11 + f[8]*v21) * w1;
        float t22 = (f[6]*v02 + f[7]*v12 + f[8]*v22) * w2;

        // out = T * V^T (+ water on diagonal)
        float o[9];
        o[0] = t00*v00 + t01*v01 + t02*v02 + wd;
        o[1] = t00*v10 + t01*v11 + t02*v12;
        o[2] = t00*v20 + t01*v21 + t02*v22;
        o[3] = t10*v00 + t11*v01 + t12*v02;
        o[4] = t10*v10 + t11*v11 + t12*v12 + wd;
        o[5] = t10*v20 + t11*v21 + t12*v22;
        o[6] = t20*v00 + t21*v01 + t22*v02;
        o[7] = t20*v10 + t21*v11 + t22*v12;
        o[8] = t20*v20 + t21*v21 + t22*v22 + wd;

        #pragma unroll
        for (int k = 0; k < 9; ++k) lds[tid * 9 + k] = o[k];
    }
    __syncthreads();

    // ---- phase 3: coalesced float4 stores (f32 output) ----
    if (nhere == 256) {
        float4* g4 = reinterpret_cast<float4*>(gOut + (size_t)pbase * 9);
        const float4* l4 = reinterpret_cast<const float4*>(lds);
        g4[tid]       = l4[tid];
        g4[tid + 256] = l4[tid + 256];
        if (tid < 64) g4[tid + 512] = l4[tid + 512];
    } else {
        for (int j = tid; j < nflt; j += 256)
            gOut[(size_t)pbase * 9 + j] = lds[j];
    }
}

extern "C" void kernel_launch(void* const* d_in, const int* in_sizes, int n_in,
                              void* d_out, int out_size, void* d_ws, size_t ws_size,
                              hipStream_t stream) {
    const float* F      = (const float*)d_in[0];
    const float* p_Elog = (const float*)d_in[1];
    const float* p_nu   = (const float*)d_in[2];
    const float* p_ys   = (const float*)d_in[3];
    const float* p_al   = (const float*)d_in[4];
    const float* p_co   = (const float*)d_in[5];
    float* out = (float*)d_out;

    const int B = in_sizes[0] / 9;
    const int nblocks = (B + 255) / 256;
    physics_svd_kernel<<<nblocks, 256, 0, stream>>>(
        F, p_Elog, p_nu, p_ys, p_al, p_co, out, B);
}

// Round 4
// 112.249 us; speedup vs baseline: 1.1246x; 1.1246x over previous
//
#include <hip/hip_runtime.h>
#include <hip/hip_bf16.h>

#define FRCP(x)  __builtin_amdgcn_rcpf(x)
#define FSQRT(x) __builtin_amdgcn_sqrtf(x)
#define FRSQ(x)  __builtin_amdgcn_rsqf(x)

// One thread = one particle. 256 particles/block.
// LDS staging: 256*9 floats in (float4-coalesced), compute in registers,
// write f32 results back into same LDS slots, float4-coalesced stores.
// Numerics (all safe under the 2.39e-2 bf16 threshold):
//  - eigen(F^T F) via 3 cyclic Jacobi sweeps, branch-free rotations,
//    fast rcp/sqrt/rsq intrinsics (no precise-div sequences)
//  - ONE off-diagonal pair rotated per (p,q) — 3x3 Jacobi touches exactly one
//    (round-3 bug: rotating it twice corrupts the eigensystem)
//  - sigma never materialized: log(max(sqrt(a),c)) = 0.5*log(max(a,c^2)),
//    1/sigma = rsqrt(a)
//  - sand logs derived from plasticine logs by select
//  - branchless von Mises / Drucker-Prager return mapping
__global__ __launch_bounds__(256) void physics_svd_kernel(
    const float* __restrict__ gF,
    const float* __restrict__ p_Elog,
    const float* __restrict__ p_nu,
    const float* __restrict__ p_ys,
    const float* __restrict__ p_alpha,
    const float* __restrict__ p_coh,
    float* __restrict__ gOut,
    int B)
{
    __shared__ __align__(16) float lds[2304];   // 256 particles * 9 floats

    const int tid   = threadIdx.x;
    const int pbase = blockIdx.x * 256;
    const int nhere = min(256, B - pbase);
    const int nflt  = nhere * 9;

    // ---- phase 1: stage F into LDS, coalesced ----
    if (nhere == 256) {
        const float4* g4 = reinterpret_cast<const float4*>(gF + (size_t)pbase * 9);
        float4* l4 = reinterpret_cast<float4*>(lds);
        l4[tid]       = g4[tid];
        l4[tid + 256] = g4[tid + 256];
        if (tid < 64) l4[tid + 512] = g4[tid + 512];
    } else {
        for (int j = tid; j < nflt; j += 256) lds[j] = gF[(size_t)pbase * 9 + j];
    }
    __syncthreads();

    // material scalars (uniform broadcast loads -> SGPRs)
    const float E  = __expf(p_Elog[0]);
    const float nu = p_nu[0];
    const float ys = p_ys[0];
    const float al = p_alpha[0];
    const float co = p_coh[0];
    const float mu = E / (2.0f * (1.0f + nu));
    const float la = E * nu / ((1.0f + nu) * (1.0f - 2.0f * nu));
    const float ys_2mu = ys / (2.0f * mu);
    const float kk     = (3.0f * la + 2.0f * mu) / (2.0f * mu) * al;
    const float exp_co = __expf(co);

    if (tid < nhere) {
        float f[9];
        #pragma unroll
        for (int k = 0; k < 9; ++k) f[k] = lds[tid * 9 + k];

        // A = F^T F (symmetric)
        float a00 = f[0]*f[0] + f[3]*f[3] + f[6]*f[6];
        float a01 = f[0]*f[1] + f[3]*f[4] + f[6]*f[7];
        float a02 = f[0]*f[2] + f[3]*f[5] + f[6]*f[8];
        float a11 = f[1]*f[1] + f[4]*f[4] + f[7]*f[7];
        float a12 = f[1]*f[2] + f[4]*f[5] + f[7]*f[8];
        float a22 = f[2]*f[2] + f[5]*f[5] + f[8]*f[8];

        float v00=1.f, v01=0.f, v02=0.f;
        float v10=0.f, v11=1.f, v12=0.f;
        float v20=0.f, v21=0.f, v22=1.f;

        // branch-free Jacobi rotation: diag pair (APP,AQQ), pivot APQ,
        // ONE off-diagonal pair (RP,RQ), V columns p,q.
        #define JROT(APP, AQQ, APQ, RP, RQ, VP0, VQ0, VP1, VQ1, VP2, VQ2)             \
        {                                                                             \
            float apq = APQ;                                                          \
            float theta = (AQQ - APP) * FRCP(2.0f * apq);                             \
            float t = copysignf(FRCP(fabsf(theta) + FSQRT(theta*theta + 1.0f)),       \
                                theta);                                               \
            t = (apq == 0.0f) ? 0.0f : t;   /* NaN guard: apq==0 && d==0 */           \
            float c = FRSQ(t*t + 1.0f);                                               \
            float s = t * c;                                                          \
            APP -= t * apq;  AQQ += t * apq;  APQ = 0.0f;                             \
            float pk = RP, qk = RQ;                                                   \
            RP = c*pk - s*qk;  RQ = s*pk + c*qk;                                      \
            float tmp;                                                                \
            tmp = VP0; VP0 = c*tmp - s*VQ0; VQ0 = s*tmp + c*VQ0;                      \
            tmp = VP1; VP1 = c*tmp - s*VQ1; VQ1 = s*tmp + c*VQ1;                      \
            tmp = VP2; VP2 = c*tmp - s*VQ2; VQ2 = s*tmp + c*VQ2;                      \
        }

        #pragma unroll
        for (int sweep = 0; sweep < 3; ++sweep) {
            // (0,1): off-diag pair (a02,a12)
            JROT(a00, a11, a01, a02, a12, v00, v01, v10, v11, v20, v21)
            // (0,2): off-diag pair (a01,a12)
            JROT(a00, a22, a02, a01, a12, v00, v02, v10, v12, v20, v22)
            // (1,2): off-diag pair (a01,a02)
            JROT(a11, a22, a12, a01, a02, v01, v02, v11, v12, v21, v22)
        }
        #undef JROT

        // eigenvalues a00,a11,a22 = sigma^2 (clamp tiny negatives)
        a00 = fmaxf(a00, 0.0f);
        a11 = fmaxf(a11, 0.0f);
        a22 = fmaxf(a22, 0.0f);

        // ---- plasticine logs: e = log(max(sigma,0.01)) = 0.5*log(max(a,1e-4)) ----
        float e0 = 0.5f * __logf(fmaxf(a00, 1e-4f));
        float e1 = 0.5f * __logf(fmaxf(a11, 1e-4f));
        float e2 = 0.5f * __logf(fmaxf(a22, 1e-4f));

        // ---- sand logs via select: h = (a>=0.0025) ? e : log(0.05) ----
        const float HLOG = -2.9957323f;  // log(0.05)
        float h0 = (a00 >= 2.5e-3f) ? e0 : HLOG;
        float h1 = (a11 >= 2.5e-3f) ? e1 : HLOG;
        float h2 = (a22 >= 2.5e-3f) ? e2 : HLOG;

        // ---- plasticine (von Mises), branchless ----
        float tr3 = (e0 + e1 + e2) * (1.0f/3.0f);
        float b0 = e0 - tr3, b1 = e1 - tr3, b2 = e2 - tr3;
        float bn = FSQRT(b0*b0 + b1*b1 + b2*b2) + 1e-5f;
        float rp = fmaxf(bn - ys_2mu, 0.0f) * FRCP(bn);
        float gp0 = __expf(e0 - rp*b0);
        float gp1 = __expf(e1 - rp*b1);
        float gp2 = __expf(e2 - rp*b2);

        // ---- sand (Drucker-Prager), branchless ----
        float trs = h0 + h1 + h2;
        float t3  = trs * (1.0f/3.0f);
        float hb0 = h0 - t3, hb1 = h1 - t3, hb2 = h2 - t3;
        float hn = FSQRT(hb0*hb0 + hb1*hb1 + hb2*hb2);
        float st = trs - 3.0f * co;
        bool cond = st < 0.0f;
        float dg = hn + kk * st;
        float rs = fmaxf(dg, 0.0f) * FRCP(hn);
        float gs0 = cond ? __expf(h0 - rs*hb0) : exp_co;
        float gs1 = cond ? __expf(h1 - rs*hb1) : exp_co;
        float gs2 = cond ? __expf(h2 - rs*hb2) : exp_co;

        // spectral weights: U diag(g) V^T = F V diag(g/sigma) V^T, 1/sigma = rsqrt(a)
        float w0 = (0.5f*gp0 + 0.3f*gs0) * FRSQ(a00);
        float w1 = (0.5f*gp1 + 0.3f*gs1) * FRSQ(a11);
        float w2 = (0.5f*gp2 + 0.3f*gs2) * FRSQ(a22);

        // water: 0.2 * J^(1/3) * I
        float J = f[0]*(f[4]*f[8] - f[5]*f[7])
                - f[1]*(f[3]*f[8] - f[5]*f[6])
                + f[2]*(f[3]*f[7] - f[4]*f[6]);
        float wd = 0.2f * __powf(J, 1.0f/3.0f);

        // T = (F V) * diag(w)
        float t00 = (f[0]*v00 + f[1]*v10 + f[2]*v20) * w0;
        float t01 = (f[0]*v01 + f[1]*v11 + f[2]*v21) * w1;
        float t02 = (f[0]*v02 + f[1]*v12 + f[2]*v22) * w2;
        float t10 = (f[3]*v00 + f[4]*v10 + f[5]*v20) * w0;
        float t11 = (f[3]*v01 + f[4]*v11 + f[5]*v21) * w1;
        float t12 = (f[3]*v02 + f[4]*v12 + f[5]*v22) * w2;
        float t20 = (f[6]*v00 + f[7]*v10 + f[8]*v20) * w0;
        float t21 = (f[6]*v01 + f[7]*v11 + f[8]*v21) * w1;
        float t22 = (f[6]*v02 + f[7]*v12 + f[8]*v22) * w2;

        // out = T * V^T (+ water on diagonal)
        float o[9];
        o[0] = t00*v00 + t01*v01 + t02*v02 + wd;
        o[1] = t00*v10 + t01*v11 + t02*v12;
        o[2] = t00*v20 + t01*v21 + t02*v22;
        o[3] = t10*v00 + t11*v01 + t12*v02;
        o[4] = t10*v10 + t11*v11 + t12*v12 + wd;
        o[5] = t10*v20 + t11*v21 + t12*v22;
        o[6] = t20*v00 + t21*v01 + t22*v02;
        o[7] = t20*v10 + t21*v11 + t22*v12;
        o[8] = t20*v20 + t21*v21 + t22*v22 + wd;

        #pragma unroll
        for (int k = 0; k < 9; ++k) lds[tid * 9 + k] = o[k];
    }
    __syncthreads();

    // ---- phase 3: coalesced float4 stores (f32 output) ----
    if (nhere == 256) {
        float4* g4 = reinterpret_cast<float4*>(gOut + (size_t)pbase * 9);
        const float4* l4 = reinterpret_cast<const float4*>(lds);
        g4[tid]       = l4[tid];
        g4[tid + 256] = l4[tid + 256];
        if (tid < 64) g4[tid + 512] = l4[tid + 512];
    } else {
        for (int j = tid; j < nflt; j += 256)
            gOut[(size_t)pbase * 9 + j] = lds[j];
    }
}

extern "C" void kernel_launch(void* const* d_in, const int* in_sizes, int n_in,
                              void* d_out, int out_size, void* d_ws, size_t ws_size,
                              hipStream_t stream) {
    const float* F      = (const float*)d_in[0];
    const float* p_Elog = (const float*)d_in[1];
    const float* p_nu   = (const float*)d_in[2];
    const float* p_ys   = (const float*)d_in[3];
    const float* p_al   = (const float*)d_in[4];
    const float* p_co   = (const float*)d_in[5];
    float* out = (float*)d_out;

    const int B = in_sizes[0] / 9;
    const int nblocks = (B + 255) / 256;
    physics_svd_kernel<<<nblocks, 256, 0, stream>>>(
        F, p_Elog, p_nu, p_ys, p_al, p_co, out, B);
}

// Round 7
// 106.789 us; speedup vs baseline: 1.1821x; 1.0511x over previous
//
#include <hip/hip_runtime.h>
#include <hip/hip_bf16.h>

#define FRCP(x)  __builtin_amdgcn_rcpf(x)
#define FSQRT(x) __builtin_amdgcn_sqrtf(x)
#define FRSQ(x)  __builtin_amdgcn_rsqf(x)
#define FLOG2(x) __builtin_amdgcn_logf(x)    // v_log_f32: log2(x)
#define FEXP2(x) __builtin_amdgcn_exp2f(x)   // v_exp_f32: 2^x

// One thread = one particle. 256 particles/block.
// LDS staging: 256*9 floats in (float4-coalesced), compute in registers,
// write f32 results back into same LDS slots, float4-coalesced stores.
// Numerics (all safe under the 2.39e-2 bf16 threshold):
//  - eigen(F^T F) via THREE cyclic Jacobi sweeps. Two sweeps FAILED on HW
//    (absmax 0.032 > 0.024, round 6): 1M-sample tail of the 2-sweep residual
//    is ~3e-2. Three sweeps sit at the bf16 floor (0.0078). Do not reduce.
//  - 3-transcendental rotation: t = 2*apq*copysign(rcp(|d|+sqrt(d^2+4apq^2)), d)
//  - ONE off-diagonal pair rotated per (p,q) (rotating twice = round-3 bug)
//  - sigma never materialized: log(max(sqrt(a),c)) = 0.5*log(max(a,c^2)),
//    1/sigma = rsqrt(a)
//  - sand logs derived from plasticine logs by select
//  - branchless von Mises / Drucker-Prager return mapping
//  - raw v_log_f32/v_exp_f32 for all log/exp (no libm wrapper fixup code)
//  - cbrt(J) = exp2(log2(J)/3), J>0 for near-identity F
__global__ __launch_bounds__(256) void physics_svd_kernel(
    const float* __restrict__ gF,
    const float* __restrict__ p_Elog,
    const float* __restrict__ p_nu,
    const float* __restrict__ p_ys,
    const float* __restrict__ p_alpha,
    const float* __restrict__ p_coh,
    float* __restrict__ gOut,
    int B)
{
    __shared__ __align__(16) float lds[2304];   // 256 particles * 9 floats

    const int tid   = threadIdx.x;
    const int pbase = blockIdx.x * 256;
    const int nhere = min(256, B - pbase);
    const int nflt  = nhere * 9;

    // ---- phase 1: stage F into LDS, coalesced ----
    if (nhere == 256) {
        const float4* g4 = reinterpret_cast<const float4*>(gF + (size_t)pbase * 9);
        float4* l4 = reinterpret_cast<float4*>(lds);
        l4[tid]       = g4[tid];
        l4[tid + 256] = g4[tid + 256];
        if (tid < 64) l4[tid + 512] = g4[tid + 512];
    } else {
        for (int j = tid; j < nflt; j += 256) lds[j] = gF[(size_t)pbase * 9 + j];
    }
    __syncthreads();

    // material scalars (uniform broadcast loads -> SGPRs)
    const float E  = __expf(p_Elog[0]);
    const float nu = p_nu[0];
    const float ys = p_ys[0];
    const float al = p_alpha[0];
    const float co = p_coh[0];
    const float mu = E / (2.0f * (1.0f + nu));
    const float la = E * nu / ((1.0f + nu) * (1.0f - 2.0f * nu));
    const float ys_2mu = ys / (2.0f * mu);
    const float kk     = (3.0f * la + 2.0f * mu) / (2.0f * mu) * al;
    const float exp_co = __expf(co);

    if (tid < nhere) {
        float f[9];
        #pragma unroll
        for (int k = 0; k < 9; ++k) f[k] = lds[tid * 9 + k];

        // A = F^T F (symmetric)
        float a00 = f[0]*f[0] + f[3]*f[3] + f[6]*f[6];
        float a01 = f[0]*f[1] + f[3]*f[4] + f[6]*f[7];
        float a02 = f[0]*f[2] + f[3]*f[5] + f[6]*f[8];
        float a11 = f[1]*f[1] + f[4]*f[4] + f[7]*f[7];
        float a12 = f[1]*f[2] + f[4]*f[5] + f[7]*f[8];
        float a22 = f[2]*f[2] + f[5]*f[5] + f[8]*f[8];

        float v00=1.f, v01=0.f, v02=0.f;
        float v10=0.f, v11=1.f, v12=0.f;
        float v20=0.f, v21=0.f, v22=1.f;

        // branch-free Jacobi rotation: diag pair (APP,AQQ), pivot APQ,
        // ONE off-diagonal pair (RP,RQ), V columns p,q.
        #define JROT(APP, AQQ, APQ, RP, RQ, VP0, VQ0, VP1, VQ1, VP2, VQ2)             \
        {                                                                             \
            float apq = APQ;                                                          \
            float d   = AQQ - APP;                                                    \
            float p2  = apq + apq;                                                    \
            float h   = FSQRT(__builtin_fmaf(d, d, p2 * p2));                         \
            float w_  = FRCP(fabsf(d) + h);                                           \
            float t   = p2 * copysignf(w_, d);                                        \
            t = (apq == 0.0f) ? 0.0f : t;   /* NaN guard: apq==0 && d==0 */           \
            float c = FRSQ(__builtin_fmaf(t, t, 1.0f));                               \
            float s = t * c;                                                          \
            APP -= t * apq;  AQQ += t * apq;  APQ = 0.0f;                             \
            float pk = RP, qk = RQ;                                                   \
            RP = c*pk - s*qk;  RQ = s*pk + c*qk;                                      \
            float tmp;                                                                \
            tmp = VP0; VP0 = c*tmp - s*VQ0; VQ0 = s*tmp + c*VQ0;                      \
            tmp = VP1; VP1 = c*tmp - s*VQ1; VQ1 = s*tmp + c*VQ1;                      \
            tmp = VP2; VP2 = c*tmp - s*VQ2; VQ2 = s*tmp + c*VQ2;                      \
        }

        #pragma unroll
        for (int sweep = 0; sweep < 3; ++sweep) {
            // (0,1): off-diag pair (a02,a12)
            JROT(a00, a11, a01, a02, a12, v00, v01, v10, v11, v20, v21)
            // (0,2): off-diag pair (a01,a12)
            JROT(a00, a22, a02, a01, a12, v00, v02, v10, v12, v20, v22)
            // (1,2): off-diag pair (a01,a02)
            JROT(a11, a22, a12, a01, a02, v01, v02, v11, v12, v21, v22)
        }
        #undef JROT

        // eigenvalues a00,a11,a22 = sigma^2 (clamp tiny negatives)
        a00 = fmaxf(a00, 0.0f);
        a11 = fmaxf(a11, 0.0f);
        a22 = fmaxf(a22, 0.0f);

        // ---- plasticine logs: e = log(max(sigma,0.01)) = 0.5*log(max(a,1e-4)) ----
        const float LN2_HALF = 0.34657359f;   // 0.5*ln2 (log2 -> 0.5*natural log)
        float e0 = LN2_HALF * FLOG2(fmaxf(a00, 1e-4f));
        float e1 = LN2_HALF * FLOG2(fmaxf(a11, 1e-4f));
        float e2 = LN2_HALF * FLOG2(fmaxf(a22, 1e-4f));

        // ---- sand logs via select: h = (a>=0.0025) ? e : log(0.05) ----
        const float HLOG = -2.9957323f;  // log(0.05)
        float h0 = (a00 >= 2.5e-3f) ? e0 : HLOG;
        float h1 = (a11 >= 2.5e-3f) ? e1 : HLOG;
        float h2 = (a22 >= 2.5e-3f) ? e2 : HLOG;

        // ---- plasticine (von Mises), branchless ----
        const float INV_LN2 = 1.4426950f;     // 1/ln2 for exp(x)=exp2(x/ln2)
        float tr3 = (e0 + e1 + e2) * (1.0f/3.0f);
        float b0 = e0 - tr3, b1 = e1 - tr3, b2 = e2 - tr3;
        float bn = FSQRT(b0*b0 + b1*b1 + b2*b2) + 1e-5f;
        float rp = fmaxf(bn - ys_2mu, 0.0f) * FRCP(bn);
        float gp0 = FEXP2((e0 - rp*b0) * INV_LN2);
        float gp1 = FEXP2((e1 - rp*b1) * INV_LN2);
        float gp2 = FEXP2((e2 - rp*b2) * INV_LN2);

        // ---- sand (Drucker-Prager), branchless ----
        float trs = h0 + h1 + h2;
        float t3  = trs * (1.0f/3.0f);
        float hb0 = h0 - t3, hb1 = h1 - t3, hb2 = h2 - t3;
        float hn = FSQRT(hb0*hb0 + hb1*hb1 + hb2*hb2);
        float st = trs - 3.0f * co;
        bool cond = st < 0.0f;
        float dg = hn + kk * st;
        float rs = fmaxf(dg, 0.0f) * FRCP(hn);
        float gs0 = cond ? FEXP2((h0 - rs*hb0) * INV_LN2) : exp_co;
        float gs1 = cond ? FEXP2((h1 - rs*hb1) * INV_LN2) : exp_co;
        float gs2 = cond ? FEXP2((h2 - rs*hb2) * INV_LN2) : exp_co;

        // spectral weights: U diag(g) V^T = F V diag(g/sigma) V^T, 1/sigma = rsqrt(a)
        float w0 = (0.5f*gp0 + 0.3f*gs0) * FRSQ(a00);
        float w1 = (0.5f*gp1 + 0.3f*gs1) * FRSQ(a11);
        float w2 = (0.5f*gp2 + 0.3f*gs2) * FRSQ(a22);

        // water: 0.2 * J^(1/3) * I  (J>0 for near-identity F)
        float J = f[0]*(f[4]*f[8] - f[5]*f[7])
                - f[1]*(f[3]*f[8] - f[5]*f[6])
                + f[2]*(f[3]*f[7] - f[4]*f[6]);
        float wd = 0.2f * FEXP2(FLOG2(J) * (1.0f/3.0f));

        // T = (F V) * diag(w)
        float t00 = (f[0]*v00 + f[1]*v10 + f[2]*v20) * w0;
        float t01 = (f[0]*v01 + f[1]*v11 + f[2]*v21) * w1;
        float t02 = (f[0]*v02 + f[1]*v12 + f[2]*v22) * w2;
        float t10 = (f[3]*v00 + f[4]*v10 + f[5]*v20) * w0;
        float t11 = (f[3]*v01 + f[4]*v11 + f[5]*v21) * w1;
        float t12 = (f[3]*v02 + f[4]*v12 + f[5]*v22) * w2;
        float t20 = (f[6]*v00 + f[7]*v10 + f[8]*v20) * w0;
        float t21 = (f[6]*v01 + f[7]*v11 + f[8]*v21) * w1;
        float t22 = (f[6]*v02 + f[7]*v12 + f[8]*v22) * w2;

        // out = T * V^T (+ water on diagonal)
        float o[9];
        o[0] = t00*v00 + t01*v01 + t02*v02 + wd;
        o[1] = t00*v10 + t01*v11 + t02*v12;
        o[2] = t00*v20 + t01*v21 + t02*v22;
        o[3] = t10*v00 + t11*v01 + t12*v02;
        o[4] = t10*v10 + t11*v11 + t12*v12 + wd;
        o[5] = t10*v20 + t11*v21 + t12*v22;
        o[6] = t20*v00 + t21*v01 + t22*v02;
        o[7] = t20*v10 + t21*v11 + t22*v12;
        o[8] = t20*v20 + t21*v21 + t22*v22 + wd;

        #pragma unroll
        for (int k = 0; k < 9; ++k) lds[tid * 9 + k] = o[k];
    }
    __syncthreads();

    // ---- phase 3: coalesced float4 stores (f32 output) ----
    if (nhere == 256) {
        float4* g4 = reinterpret_cast<float4*>(gOut + (size_t)pbase * 9);
        const float4* l4 = reinterpret_cast<const float4*>(lds);
        g4[tid]       = l4[tid];
        g4[tid + 256] = l4[tid + 256];
        if (tid < 64) g4[tid + 512] = l4[tid + 512];
    } else {
        for (int j = tid; j < nflt; j += 256)
            gOut[(size_t)pbase * 9 + j] = lds[j];
    }
}

extern "C" void kernel_launch(void* const* d_in, const int* in_sizes, int n_in,
                              void* d_out, int out_size, void* d_ws, size_t ws_size,
                              hipStream_t stream) {
    const float* F      = (const float*)d_in[0];
    const float* p_Elog = (const float*)d_in[1];
    const float* p_nu   = (const float*)d_in[2];
    const float* p_ys   = (const float*)d_in[3];
    const float* p_al   = (const float*)d_in[4];
    const float* p_co   = (const float*)d_in[5];
    float* out = (float*)d_out;

    const int B = in_sizes[0] / 9;
    const int nblocks = (B + 255) / 256;
    physics_svd_kernel<<<nblocks, 256, 0, stream>>>(
        F, p_Elog, p_nu, p_ys, p_al, p_co, out, B);
}

// Round 8
// 102.071 us; speedup vs baseline: 1.2368x; 1.0462x over previous
//
#include <hip/hip_runtime.h>
#include <hip/hip_bf16.h>

#define FRCP(x)  __builtin_amdgcn_rcpf(x)
#define FSQRT(x) __builtin_amdgcn_sqrtf(x)
#define FRSQ(x)  __builtin_amdgcn_rsqf(x)
#define FLOG2(x) __builtin_amdgcn_logf(x)    // v_log_f32: log2(x)
#define FEXP2(x) __builtin_amdgcn_exp2f(x)   // v_exp_f32: 2^x

// One thread = one particle. 256 particles/block.
// LDS staging: float4-coalesced in, compute in registers, float4-coalesced out.
//
// KEY STRUCTURE (round 8): no eigenvectors. Output = F * p(A) + wd*I where
// A = F^T F and p is the quadratic with p(lambda_i) = w_i (Newton form).
// Matrix-function interpolation is well-conditioned at the spectrum: divided-
// difference rounding is multiplied by (lambda - node) factors ~ gap, so the
// gap-amplified eigenvector-mixing error (round-6 failure) cannot occur.
//
// LOCKED decisions (HW-tested):
//  - THREE Jacobi sweeps: 2 sweeps FAILED round 6 (absmax 0.032 > 0.024).
//    (That failure was V-mixing; with matrix-function 2 sweeps may be safe,
//    but 3 is the proven config.)
//  - ONE off-diagonal pair rotated per (p,q) (rotating twice = round-3 bug).
//  - f32 output buffer (bf16 store failed round 1).
//  - fast rcp/sqrt/rsq + raw v_log_f32/v_exp_f32: absmax stays at bf16 floor.
// Numerics:
//  - 3-transcendental rotation: t = 2*apq*copysign(rcp(|d|+sqrt(d^2+4apq^2)),d)
//  - clamps done in log2 domain: max(log2 a, log2 c) == log2(max(a,c))
//  - sigma powers folded into exp2 arguments (no rsq anywhere)
//  - divided-difference denominators floored at 1e-6 (sign-preserving)
//  - cbrt(J) = exp2(log2(J)/3), J>0 for near-identity F
__global__ __launch_bounds__(256) void physics_svd_kernel(
    const float* __restrict__ gF,
    const float* __restrict__ p_Elog,
    const float* __restrict__ p_nu,
    const float* __restrict__ p_ys,
    const float* __restrict__ p_alpha,
    const float* __restrict__ p_coh,
    float* __restrict__ gOut,
    int B)
{
    __shared__ __align__(16) float lds[2304];   // 256 particles * 9 floats

    const int tid   = threadIdx.x;
    const int pbase = blockIdx.x * 256;
    const int nhere = min(256, B - pbase);
    const int nflt  = nhere * 9;

    // ---- phase 1: stage F into LDS, coalesced ----
    if (nhere == 256) {
        const float4* g4 = reinterpret_cast<const float4*>(gF + (size_t)pbase * 9);
        float4* l4 = reinterpret_cast<float4*>(lds);
        l4[tid]       = g4[tid];
        l4[tid + 256] = g4[tid + 256];
        if (tid < 64) l4[tid + 512] = g4[tid + 512];
    } else {
        for (int j = tid; j < nflt; j += 256) lds[j] = gF[(size_t)pbase * 9 + j];
    }
    __syncthreads();

    // material scalars (uniform broadcast loads -> SGPRs)
    const float E  = __expf(p_Elog[0]);
    const float nu = p_nu[0];
    const float ys = p_ys[0];
    const float al = p_alpha[0];
    const float co = p_coh[0];
    const float mu = E / (2.0f * (1.0f + nu));
    const float la = E * nu / ((1.0f + nu) * (1.0f - 2.0f * nu));
    const float ys_2mu = ys / (2.0f * mu);
    const float kk     = (3.0f * la + 2.0f * mu) / (2.0f * mu) * al;
    const float lco2   = co * 1.4426950f;   // log2(exp(co))

    const float LN2      = 0.69314718f;
    const float L2_1EM4  = -13.287712f;     // log2(1e-4)   (sigma floor 0.01)
    const float L2_25EM4 = -8.6438562f;     // log2(2.5e-3) (sigma floor 0.05)

    if (tid < nhere) {
        float f[9];
        #pragma unroll
        for (int k = 0; k < 9; ++k) f[k] = lds[tid * 9 + k];

        // A = F^T F (symmetric) — keep originals b* for the polynomial
        float b00 = f[0]*f[0] + f[3]*f[3] + f[6]*f[6];
        float b01 = f[0]*f[1] + f[3]*f[4] + f[6]*f[7];
        float b02 = f[0]*f[2] + f[3]*f[5] + f[6]*f[8];
        float b11 = f[1]*f[1] + f[4]*f[4] + f[7]*f[7];
        float b12 = f[1]*f[2] + f[4]*f[5] + f[7]*f[8];
        float b22 = f[2]*f[2] + f[5]*f[5] + f[8]*f[8];

        float a00 = b00, a01 = b01, a02 = b02;
        float a11 = b11, a12 = b12, a22 = b22;

        // Jacobi rotation, eigenvalues only (no V accumulation):
        // diag pair (APP,AQQ), pivot APQ, ONE off-diagonal pair (RP,RQ).
        #define JROT(APP, AQQ, APQ, RP, RQ)                                           \
        {                                                                             \
            float apq = APQ;                                                          \
            float d   = AQQ - APP;                                                    \
            float p2  = apq + apq;                                                    \
            float h   = FSQRT(__builtin_fmaf(d, d, p2 * p2));                         \
            float w_  = FRCP(fabsf(d) + h);                                           \
            float t   = p2 * copysignf(w_, d);                                        \
            t = (apq == 0.0f) ? 0.0f : t;   /* NaN guard: apq==0 && d==0 */           \
            float c = FRSQ(__builtin_fmaf(t, t, 1.0f));                               \
            float s = t * c;                                                          \
            APP -= t * apq;  AQQ += t * apq;  APQ = 0.0f;                             \
            float pk = RP, qk = RQ;                                                   \
            RP = c*pk - s*qk;  RQ = s*pk + c*qk;                                      \
        }

        #pragma unroll
        for (int sweep = 0; sweep < 3; ++sweep) {
            JROT(a00, a11, a01, a02, a12)   // (0,1): off-diag pair (a02,a12)
            JROT(a00, a22, a02, a01, a12)   // (0,2): off-diag pair (a01,a12)
            JROT(a11, a22, a12, a01, a02)   // (1,2): off-diag pair (a01,a02)
        }
        #undef JROT

        // eigenvalues (unordered) = sigma^2
        float l0 = fmaxf(a00, 1e-20f);
        float l1 = fmaxf(a11, 1e-20f);
        float l2 = fmaxf(a22, 1e-20f);
        float li0 = FLOG2(l0), li1 = FLOG2(l1), li2 = FLOG2(l2);

        // ---- plasticine (von Mises) in log2 domain ----
        // eta_i = log2(max(sigma,0.01)) = max(li,-13.288)/2
        float p0 = 0.5f * fmaxf(li0, L2_1EM4);
        float p1 = 0.5f * fmaxf(li1, L2_1EM4);
        float p2 = 0.5f * fmaxf(li2, L2_1EM4);
        float mp = (p0 + p1 + p2) * (1.0f/3.0f);
        float bb0 = p0 - mp, bb1 = p1 - mp, bb2 = p2 - mp;
        float bn = LN2 * FSQRT(bb0*bb0 + bb1*bb1 + bb2*bb2) + 1e-5f;  // natural norm
        float rp = fmaxf(bn - ys_2mu, 0.0f) * FRCP(bn);

        // ---- sand (Drucker-Prager) in log2 domain ----
        float q0 = 0.5f * fmaxf(li0, L2_25EM4);
        float q1 = 0.5f * fmaxf(li1, L2_25EM4);
        float q2 = 0.5f * fmaxf(li2, L2_25EM4);
        float mq = (q0 + q1 + q2) * (1.0f/3.0f);
        float hb0 = q0 - mq, hb1 = q1 - mq, hb2 = q2 - mq;
        float hn = LN2 * FSQRT(hb0*hb0 + hb1*hb1 + hb2*hb2);          // natural norm
        float st = LN2 * (q0 + q1 + q2) - 3.0f * co;                  // natural trace
        bool cond = st < 0.0f;
        float rs = fmaxf(hn + kk * st, 0.0f) * FRCP(fmaxf(hn, 1e-20f));

        // ---- spectral weights w_i = (0.5*gp_i + 0.3*gs_i)/sigma_i ----
        // gp_i/sigma = exp2(eta_i - rp*bb_i - li/2); sand analog; !cond: exp(co)/sigma
        float hl0 = 0.5f * li0, hl1 = 0.5f * li1, hl2 = 0.5f * li2;
        float w0 = 0.5f * FEXP2(p0 - rp*bb0 - hl0)
                 + 0.3f * FEXP2(cond ? (q0 - rs*hb0 - hl0) : (lco2 - hl0));
        float w1 = 0.5f * FEXP2(p1 - rp*bb1 - hl1)
                 + 0.3f * FEXP2(cond ? (q1 - rs*hb1 - hl1) : (lco2 - hl1));
        float w2 = 0.5f * FEXP2(p2 - rp*bb2 - hl2)
                 + 0.3f * FEXP2(cond ? (q2 - rs*hb2 - hl2) : (lco2 - hl2));

        // ---- Newton-form matrix function: p(A) = c0 + c1(A-l0) + c2(A-l0)(A-l1) ----
        float d10 = l1 - l0, d21 = l2 - l1, d20 = l2 - l0;
        float i10 = FRCP(copysignf(fmaxf(fabsf(d10), 1e-6f), d10));
        float i21 = FRCP(copysignf(fmaxf(fabsf(d21), 1e-6f), d21));
        float i20 = FRCP(copysignf(fmaxf(fabsf(d20), 1e-6f), d20));
        float c1  = (w1 - w0) * i10;
        float w12 = (w2 - w1) * i21;
        float c2  = (w12 - c1) * i20;
        // p(x) = c2 x^2 + beta x + alpha
        float beta  = c1 - c2 * (l0 + l1);
        float alpha = w0 - c1 * l0 + c2 * l0 * l1;

        // S = A^2 (symmetric, from ORIGINAL A)
        float s00 = b00*b00 + b01*b01 + b02*b02;
        float s01 = b00*b01 + b01*b11 + b02*b12;
        float s02 = b00*b02 + b01*b12 + b02*b22;
        float s11 = b01*b01 + b11*b11 + b12*b12;
        float s12 = b01*b02 + b11*b12 + b12*b22;
        float s22 = b02*b02 + b12*b12 + b22*b22;

        // W = c2*S + beta*A + alpha*I  (= V diag(w) V^T)
        float W00 = c2*s00 + beta*b00 + alpha;
        float W01 = c2*s01 + beta*b01;
        float W02 = c2*s02 + beta*b02;
        float W11 = c2*s11 + beta*b11 + alpha;
        float W12 = c2*s12 + beta*b12;
        float W22 = c2*s22 + beta*b22 + alpha;

        // water: 0.2 * J^(1/3) * I  (J>0 for near-identity F)
        float J = f[0]*(f[4]*f[8] - f[5]*f[7])
                - f[1]*(f[3]*f[8] - f[5]*f[6])
                + f[2]*(f[3]*f[7] - f[4]*f[6]);
        float wd = 0.2f * FEXP2(FLOG2(J) * (1.0f/3.0f));

        // out = F * W + wd * I
        float o[9];
        o[0] = f[0]*W00 + f[1]*W01 + f[2]*W02 + wd;
        o[1] = f[0]*W01 + f[1]*W11 + f[2]*W12;
        o[2] = f[0]*W02 + f[1]*W12 + f[2]*W22;
        o[3] = f[3]*W00 + f[4]*W01 + f[5]*W02;
        o[4] = f[3]*W01 + f[4]*W11 + f[5]*W12 + wd;
        o[5] = f[3]*W02 + f[4]*W12 + f[5]*W22;
        o[6] = f[6]*W00 + f[7]*W01 + f[8]*W02;
        o[7] = f[6]*W01 + f[7]*W11 + f[8]*W12;
        o[8] = f[6]*W02 + f[7]*W12 + f[8]*W22 + wd;

        #pragma unroll
        for (int k = 0; k < 9; ++k) lds[tid * 9 + k] = o[k];
    }
    __syncthreads();

    // ---- phase 3: coalesced float4 stores (f32 output) ----
    if (nhere == 256) {
        float4* g4 = reinterpret_cast<float4*>(gOut + (size_t)pbase * 9);
        const float4* l4 = reinterpret_cast<const float4*>(lds);
        g4[tid]       = l4[tid];
        g4[tid + 256] = l4[tid + 256];
        if (tid < 64) g4[tid + 512] = l4[tid + 512];
    } else {
        for (int j = tid; j < nflt; j += 256)
            gOut[(size_t)pbase * 9 + j] = lds[j];
    }
}

extern "C" void kernel_launch(void* const* d_in, const int* in_sizes, int n_in,
                              void* d_out, int out_size, void* d_ws, size_t ws_size,
                              hipStream_t stream) {
    const float* F      = (const float*)d_in[0];
    const float* p_Elog = (const float*)d_in[1];
    const float* p_nu   = (const float*)d_in[2];
    const float* p_ys   = (const float*)d_in[3];
    const float* p_al   = (const float*)d_in[4];
    const float* p_co   = (const float*)d_in[5];
    float* out = (float*)d_out;

    const int B = in_sizes[0] / 9;
    const int nblocks = (B + 255) / 256;
    physics_svd_kernel<<<nblocks, 256, 0, stream>>>(
        F, p_Elog, p_nu, p_ys, p_al, p_co, out, B);
}

// Round 9
// 99.431 us; speedup vs baseline: 1.2696x; 1.0265x over previous
//
#include <hip/hip_runtime.h>
#include <hip/hip_bf16.h>

#define FRCP(x)  __builtin_amdgcn_rcpf(x)
#define FSQRT(x) __builtin_amdgcn_sqrtf(x)
#define FLOG2(x) __builtin_amdgcn_logf(x)    // v_log_f32: log2(x)
#define FEXP2(x) __builtin_amdgcn_exp2f(x)   // v_exp_f32: 2^x

// One thread = one particle. 256 particles/block.
// LDS staging: float4-coalesced in, compute in registers, float4-coalesced out.
//
// STRUCTURE: no eigenvectors (round 8) + no eigen-iteration (round 9).
// Output = F * p(A) + wd*I, A = F^T F, p = quadratic Newton interpolation of
// the spectral weights w_i at the eigenvalues. Matrix-function form makes
// output error ~ (|p'|+|w'|)*dLambda — decoupled from eigenvector/gap
// conditioning — so closed-form trigonometric eigenvalues (Smith's method)
// with ~1e-6 accuracy are sufficient:
//   lambda = m + 2*sqrt(pp)*cos(acos(r)/3 + 2k*pi/3)
// cos(acos(r)/3) solved WITHOUT acos: root of 4c^3-3c=r in [0.5,1];
// u = sqrt((1+r)/2) removes the r=-1 sqrt-singularity; cubic fit in u
// (max err ~5e-4) + 1 guarded Newton -> dc ~1e-6.
//
// LOCKED decisions (HW-tested):
//  - f32 output buffer (bf16 store failed round 1).
//  - fast rcp/sqrt + raw v_log_f32/v_exp_f32: absmax stays at bf16 floor.
//  - (historical: 2-sweep Jacobi failed round 6 under the eigenvector
//    formulation; matrix-function form removed that failure mode in round 8.)
// Numerics:
//  - sigma floors in log2 domain: max(0.5*log2 a, log2 c) == log2(max(sqrt a,c))
//  - divided differences: magnitudes floored at 1e-6, single rcp of the
//    triple product gives all three inverses
//  - cbrt(J) = exp2(log2(J)/3), J>0 for near-identity F
__global__ __launch_bounds__(256) void physics_svd_kernel(
    const float* __restrict__ gF,
    const float* __restrict__ p_Elog,
    const float* __restrict__ p_nu,
    const float* __restrict__ p_ys,
    const float* __restrict__ p_alpha,
    const float* __restrict__ p_coh,
    float* __restrict__ gOut,
    int B)
{
    __shared__ __align__(16) float lds[2304];   // 256 particles * 9 floats

    const int tid   = threadIdx.x;
    const int pbase = blockIdx.x * 256;
    const int nhere = min(256, B - pbase);
    const int nflt  = nhere * 9;

    // ---- phase 1: stage F into LDS, coalesced ----
    if (nhere == 256) {
        const float4* g4 = reinterpret_cast<const float4*>(gF + (size_t)pbase * 9);
        float4* l4 = reinterpret_cast<float4*>(lds);
        l4[tid]       = g4[tid];
        l4[tid + 256] = g4[tid + 256];
        if (tid < 64) l4[tid + 512] = g4[tid + 512];
    } else {
        for (int j = tid; j < nflt; j += 256) lds[j] = gF[(size_t)pbase * 9 + j];
    }
    __syncthreads();

    // material scalars (uniform broadcast loads -> SGPRs)
    const float E  = __expf(p_Elog[0]);
    const float nu = p_nu[0];
    const float ys = p_ys[0];
    const float al = p_alpha[0];
    const float co = p_coh[0];
    const float mu = E / (2.0f * (1.0f + nu));
    const float la = E * nu / ((1.0f + nu) * (1.0f - 2.0f * nu));
    const float ys_2mu = ys / (2.0f * mu);
    const float kk     = (3.0f * la + 2.0f * mu) / (2.0f * mu) * al;
    const float lco2   = co * 1.4426950f;   // log2(exp(co))

    const float LN2     = 0.69314718f;
    const float L2_001  = -6.6438562f;      // log2(0.01)  (plasticine sigma floor)
    const float L2_005  = -4.3219281f;      // log2(0.05)  (sand sigma floor)

    if (tid < nhere) {
        float f[9];
        #pragma unroll
        for (int k = 0; k < 9; ++k) f[k] = lds[tid * 9 + k];

        // A = F^T F (symmetric)
        float b00 = f[0]*f[0] + f[3]*f[3] + f[6]*f[6];
        float b01 = f[0]*f[1] + f[3]*f[4] + f[6]*f[7];
        float b02 = f[0]*f[2] + f[3]*f[5] + f[6]*f[8];
        float b11 = f[1]*f[1] + f[4]*f[4] + f[7]*f[7];
        float b12 = f[1]*f[2] + f[4]*f[5] + f[7]*f[8];
        float b22 = f[2]*f[2] + f[5]*f[5] + f[8]*f[8];

        // ---- closed-form eigenvalues (Smith's trigonometric method) ----
        float m3  = (b00 + b11 + b22) * (1.0f/3.0f);
        float k00 = b00 - m3, k11 = b11 - m3, k22 = b22 - m3;
        float pp  = (k00*k00 + k11*k11 + k22*k22) * (1.0f/6.0f)
                  + (b01*b01 + b02*b02 + b12*b12) * (1.0f/3.0f);
        float qq  = 0.5f * (k00*(k11*k22 - b12*b12)
                          - b01*(b01*k22 - b12*b02)
                          + b02*(b01*b12 - k11*b02));
        float sp  = FSQRT(pp);
        float rr  = qq * FRCP(fmaxf(pp * sp, 1e-30f));
        rr = fminf(fmaxf(rr, -1.0f), 1.0f);
        // c = cos(acos(rr)/3): cubic init in u = sqrt((1+r)/2), 1 Newton on 4c^3-3c=r
        float uu = FSQRT(__builtin_fmaf(0.5f, rr, 0.5f));
        float cc = 0.5f + uu * (0.57735027f + uu * (-0.09914500f + uu * 0.02179470f));
        float c2v = cc * cc;
        float fv  = cc * __builtin_fmaf(4.0f, c2v, -3.0f) - rr;
        float fpv = __builtin_fmaf(12.0f, c2v, -3.0f);
        cc -= fv * FRCP(fmaxf(fpv, 1e-4f));
        cc = fminf(fmaxf(cc, 0.5f), 1.0f);
        float ssin = FSQRT(fmaxf(__builtin_fmaf(-cc, cc, 1.0f), 0.0f));
        float sp2 = sp + sp;
        float l0 = __builtin_fmaf(sp2, cc, m3);                         // largest
        float ca = __builtin_fmaf(-0.8660254f, ssin, -0.5f * cc);       // cos(phi+2pi/3)
        float l1 = __builtin_fmaf(sp2, ca, m3);                         // smallest
        float l2 = 3.0f * m3 - l0 - l1;                                 // middle (trace)
        l0 = fmaxf(l0, 1e-20f);
        l1 = fmaxf(l1, 1e-20f);
        l2 = fmaxf(l2, 1e-20f);

        float li0 = FLOG2(l0), li1 = FLOG2(l1), li2 = FLOG2(l2);
        float hl0 = 0.5f * li0, hl1 = 0.5f * li1, hl2 = 0.5f * li2;

        // ---- plasticine (von Mises) in log2 domain ----
        float p0 = fmaxf(hl0, L2_001);
        float p1 = fmaxf(hl1, L2_001);
        float p2 = fmaxf(hl2, L2_001);
        float mp = (p0 + p1 + p2) * (1.0f/3.0f);
        float bb0 = p0 - mp, bb1 = p1 - mp, bb2 = p2 - mp;
        float bn = LN2 * FSQRT(bb0*bb0 + bb1*bb1 + bb2*bb2) + 1e-5f;  // natural norm
        float rp = fmaxf(bn - ys_2mu, 0.0f) * FRCP(bn);

        // ---- sand (Drucker-Prager) in log2 domain ----
        float q0 = fmaxf(hl0, L2_005);
        float q1 = fmaxf(hl1, L2_005);
        float q2 = fmaxf(hl2, L2_005);
        float mq = (q0 + q1 + q2) * (1.0f/3.0f);
        float hb0 = q0 - mq, hb1 = q1 - mq, hb2 = q2 - mq;
        float hn = LN2 * FSQRT(hb0*hb0 + hb1*hb1 + hb2*hb2);          // natural norm
        float st = LN2 * (q0 + q1 + q2) - 3.0f * co;                  // natural trace
        bool cond = st < 0.0f;
        float rs = fmaxf(hn + kk * st, 0.0f) * FRCP(fmaxf(hn, 1e-20f));

        // ---- spectral weights w_i = (0.5*gp_i + 0.3*gs_i)/sigma_i ----
        float w0 = 0.5f * FEXP2(p0 - rp*bb0 - hl0)
                 + 0.3f * FEXP2(cond ? (q0 - rs*hb0 - hl0) : (lco2 - hl0));
        float w1 = 0.5f * FEXP2(p1 - rp*bb1 - hl1)
                 + 0.3f * FEXP2(cond ? (q1 - rs*hb1 - hl1) : (lco2 - hl1));
        float w2 = 0.5f * FEXP2(p2 - rp*bb2 - hl2)
                 + 0.3f * FEXP2(cond ? (q2 - rs*hb2 - hl2) : (lco2 - hl2));

        // ---- Newton-form matrix function: p(A) = w0 + c1(A-l0) + c2(A-l0)(A-l1) ----
        float d10 = l1 - l0, d21 = l2 - l1, d20 = l2 - l0;
        d10 = copysignf(fmaxf(fabsf(d10), 1e-6f), d10);
        d21 = copysignf(fmaxf(fabsf(d21), 1e-6f), d21);
        d20 = copysignf(fmaxf(fabsf(d20), 1e-6f), d20);
        float invP = FRCP(d10 * d21 * d20);       // |prod| >= 1e-18, normal f32
        float i10 = d21 * d20 * invP;
        float i21 = d10 * d20 * invP;
        float i20 = d10 * d21 * invP;
        float c1  = (w1 - w0) * i10;
        float w12 = (w2 - w1) * i21;
        float c2  = (w12 - c1) * i20;
        // p(x) = c2 x^2 + beta x + alpha
        float beta  = c1 - c2 * (l0 + l1);
        float alpha = w0 - c1 * l0 + c2 * l0 * l1;

        // S = A^2 (symmetric)
        float s00 = b00*b00 + b01*b01 + b02*b02;
        float s01 = b00*b01 + b01*b11 + b02*b12;
        float s02 = b00*b02 + b01*b12 + b02*b22;
        float s11 = b01*b01 + b11*b11 + b12*b12;
        float s12 = b01*b02 + b11*b12 + b12*b22;
        float s22 = b02*b02 + b12*b12 + b22*b22;

        // W = c2*S + beta*A + alpha*I  (= V diag(w) V^T)
        float W00 = c2*s00 + beta*b00 + alpha;
        float W01 = c2*s01 + beta*b01;
        float W02 = c2*s02 + beta*b02;
        float W11 = c2*s11 + beta*b11 + alpha;
        float W12 = c2*s12 + beta*b12;
        float W22 = c2*s22 + beta*b22 + alpha;

        // water: 0.2 * J^(1/3) * I  (J>0 for near-identity F)
        float J = f[0]*(f[4]*f[8] - f[5]*f[7])
                - f[1]*(f[3]*f[8] - f[5]*f[6])
                + f[2]*(f[3]*f[7] - f[4]*f[6]);
        float wd = 0.2f * FEXP2(FLOG2(J) * (1.0f/3.0f));

        // out = F * W + wd * I
        float o[9];
        o[0] = f[0]*W00 + f[1]*W01 + f[2]*W02 + wd;
        o[1] = f[0]*W01 + f[1]*W11 + f[2]*W12;
        o[2] = f[0]*W02 + f[1]*W12 + f[2]*W22;
        o[3] = f[3]*W00 + f[4]*W01 + f[5]*W02;
        o[4] = f[3]*W01 + f[4]*W11 + f[5]*W12 + wd;
        o[5] = f[3]*W02 + f[4]*W12 + f[5]*W22;
        o[6] = f[6]*W00 + f[7]*W01 + f[8]*W02;
        o[7] = f[6]*W01 + f[7]*W11 + f[8]*W12;
        o[8] = f[6]*W02 + f[7]*W12 + f[8]*W22 + wd;

        #pragma unroll
        for (int k = 0; k < 9; ++k) lds[tid * 9 + k] = o[k];
    }
    __syncthreads();

    // ---- phase 3: coalesced float4 stores (f32 output) ----
    if (nhere == 256) {
        float4* g4 = reinterpret_cast<float4*>(gOut + (size_t)pbase * 9);
        const float4* l4 = reinterpret_cast<const float4*>(lds);
        g4[tid]       = l4[tid];
        g4[tid + 256] = l4[tid + 256];
        if (tid < 64) g4[tid + 512] = l4[tid + 512];
    } else {
        for (int j = tid; j < nflt; j += 256)
            gOut[(size_t)pbase * 9 + j] = lds[j];
    }
}

extern "C" void kernel_launch(void* const* d_in, const int* in_sizes, int n_in,
                              void* d_out, int out_size, void* d_ws, size_t ws_size,
                              hipStream_t stream) {
    const float* F      = (const float*)d_in[0];
    const float* p_Elog = (const float*)d_in[1];
    const float* p_nu   = (const float*)d_in[2];
    const float* p_ys   = (const float*)d_in[3];
    const float* p_al   = (const float*)d_in[4];
    const float* p_co   = (const float*)d_in[5];
    float* out = (float*)d_out;

    const int B = in_sizes[0] / 9;
    const int nblocks = (B + 255) / 256;
    physics_svd_kernel<<<nblocks, 256, 0, stream>>>(
        F, p_Elog, p_nu, p_ys, p_al, p_co, out, B);
}